// Round 1
// baseline (237.177 us; speedup 1.0000x reference)
//
#include <hip/hip_runtime.h>
#include <math.h>

#define N_NODE 10
#define N_FEAT 8
#define HID 80
#define IN_DIM 40

// ---------------------------------------------------------------------------
// Fold GraphConv (fixed circulant adjacency) + W_rel/W_root + decoder into a
// single [HID x IN_DIM] matrix W_mid and bias b_mid:
//   out = relu( relu(x@W_enc + b_enc) @ W_mid + b_mid )
// W_mid[s*8+f, o] = sum_g [ W_root[f,g]*W_dec[s*8+g,o]
//                         + w*W_rel[f,g]*(W_dec[((s+1)%10)*8+g,o]
//                                        +W_dec[((s-1)%10)*8+g,o]) ]
// b_mid[o]        = sum_{t,g} b_rel[g]*W_dec[t*8+g,o] + b_dec[o]
// ---------------------------------------------------------------------------
__global__ void precompute_kernel(const float* __restrict__ W_rel,
                                  const float* __restrict__ b_rel,
                                  const float* __restrict__ W_root,
                                  const float* __restrict__ W_dec,
                                  const float* __restrict__ b_dec,
                                  float* __restrict__ W_mid,
                                  float* __restrict__ b_mid)
{
    const float w = expf(-1.0f / 9.0f);
    const int idx = blockIdx.x * blockDim.x + threadIdx.x;
    const int nthr = gridDim.x * blockDim.x;

    for (int e = idx; e < HID * IN_DIM; e += nthr) {
        const int o  = e % IN_DIM;
        const int sf = e / IN_DIM;
        const int s  = sf / N_FEAT;
        const int f  = sf % N_FEAT;
        const int sp = (s + 1) % N_NODE;
        const int sm = (s + N_NODE - 1) % N_NODE;
        float acc = 0.0f;
        #pragma unroll
        for (int g = 0; g < N_FEAT; ++g) {
            acc = fmaf(W_root[f * N_FEAT + g], W_dec[(s  * N_FEAT + g) * IN_DIM + o], acc);
            acc = fmaf(w * W_rel[f * N_FEAT + g],
                       W_dec[(sp * N_FEAT + g) * IN_DIM + o] +
                       W_dec[(sm * N_FEAT + g) * IN_DIM + o], acc);
        }
        W_mid[e] = acc;
    }

    for (int o = idx; o < IN_DIM; o += nthr) {
        float acc = b_dec[o];
        #pragma unroll
        for (int t = 0; t < N_NODE; ++t)
            #pragma unroll
            for (int g = 0; g < N_FEAT; ++g)
                acc = fmaf(b_rel[g], W_dec[(t * N_FEAT + g) * IN_DIM + o], acc);
        b_mid[o] = acc;
    }
}

// ---------------------------------------------------------------------------
// Fused 2-layer MLP, one row per thread. Accumulators live in registers with
// fully static indexing (runtime-indexed arrays would spill to scratch).
// Weight reads use wave-uniform addresses -> compiler emits s_load batches +
// v_fmac_f32 vdst, sgpr, vgpr (scalar-cache broadcast, zero LDS traffic).
// ---------------------------------------------------------------------------
__global__ __launch_bounds__(256) void fused_mlp_kernel(
    const float* __restrict__ x,
    const float* __restrict__ W_enc,   // [IN_DIM][HID]
    const float* __restrict__ b_enc,   // [HID]
    const float* __restrict__ W_mid,   // [HID][IN_DIM]
    const float* __restrict__ b_mid,   // [IN_DIM]
    float* __restrict__ out,
    int B)
{
    const int r = blockIdx.x * blockDim.x + threadIdx.x;
    if (r >= B) return;

    const float4* xp = (const float4*)(x + (size_t)r * IN_DIM);

    // ---- layer 1: y = relu(x @ W_enc + b_enc) ----
    float y[HID];
    #pragma unroll
    for (int j = 0; j < HID; ++j) y[j] = b_enc[j];

    #pragma unroll
    for (int kk = 0; kk < IN_DIM / 4; ++kk) {
        const float4 xv = xp[kk];
        const float* wrow = W_enc + (kk * 4) * HID;
        #pragma unroll
        for (int j = 0; j < HID; ++j) {
            float a = y[j];
            a = fmaf(xv.x, wrow[0 * HID + j], a);
            a = fmaf(xv.y, wrow[1 * HID + j], a);
            a = fmaf(xv.z, wrow[2 * HID + j], a);
            a = fmaf(xv.w, wrow[3 * HID + j], a);
            y[j] = a;
        }
    }
    #pragma unroll
    for (int j = 0; j < HID; ++j) y[j] = fmaxf(y[j], 0.0f);

    // ---- layer 2: out = relu(y @ W_mid + b_mid) ----
    float o[IN_DIM];
    #pragma unroll
    for (int j = 0; j < IN_DIM; ++j) o[j] = b_mid[j];

    #pragma unroll
    for (int k = 0; k < HID; ++k) {
        const float yk = y[k];
        const float* wrow = W_mid + k * IN_DIM;
        #pragma unroll
        for (int j = 0; j < IN_DIM; ++j)
            o[j] = fmaf(yk, wrow[j], o[j]);
    }

    float4* op = (float4*)(out + (size_t)r * IN_DIM);
    #pragma unroll
    for (int q = 0; q < IN_DIM / 4; ++q) {
        float4 v;
        v.x = fmaxf(o[q * 4 + 0], 0.0f);
        v.y = fmaxf(o[q * 4 + 1], 0.0f);
        v.z = fmaxf(o[q * 4 + 2], 0.0f);
        v.w = fmaxf(o[q * 4 + 3], 0.0f);
        op[q] = v;
    }
}

extern "C" void kernel_launch(void* const* d_in, const int* in_sizes, int n_in,
                              void* d_out, int out_size, void* d_ws, size_t ws_size,
                              hipStream_t stream)
{
    const float* x      = (const float*)d_in[0];
    const float* W_enc  = (const float*)d_in[1];
    const float* b_enc  = (const float*)d_in[2];
    const float* W_rel  = (const float*)d_in[3];
    const float* b_rel  = (const float*)d_in[4];
    const float* W_root = (const float*)d_in[5];
    const float* W_dec  = (const float*)d_in[6];
    const float* b_dec  = (const float*)d_in[7];
    float* out = (float*)d_out;

    const int B = in_sizes[0] / IN_DIM;

    float* W_mid = (float*)d_ws;                 // HID*IN_DIM floats
    float* b_mid = W_mid + HID * IN_DIM;         // IN_DIM floats

    precompute_kernel<<<13, 256, 0, stream>>>(W_rel, b_rel, W_root, W_dec, b_dec,
                                              W_mid, b_mid);

    const int grid = (B + 255) / 256;
    fused_mlp_kernel<<<grid, 256, 0, stream>>>(x, W_enc, b_enc, W_mid, b_mid, out, B);
}

// Round 2
// 99.569 us; speedup vs baseline: 2.3820x; 2.3820x over previous
//
#include <hip/hip_runtime.h>
#include <math.h>

#define N_NODE 10
#define N_FEAT 8
#define HID 80
#define IN_DIM 40

typedef __attribute__((ext_vector_type(8))) short bf16x8;
typedef __attribute__((ext_vector_type(4))) float f32x4;

__device__ __forceinline__ unsigned short f2bf(float f) {
    unsigned u = __builtin_bit_cast(unsigned, f);
    u += 0x7fffu + ((u >> 16) & 1u);          // round-to-nearest-even
    return (unsigned short)(u >> 16);
}

// ---------------------------------------------------------------------------
// Fold GraphConv (fixed circulant adjacency) + W_rel/W_root + decoder into
// W_mid [HID][IN_DIM] and b_mid [IN_DIM]:  out = relu(relu(x@W_enc+b_enc)@W_mid+b_mid)
// ---------------------------------------------------------------------------
__global__ void precompute_kernel(const float* __restrict__ W_rel,
                                  const float* __restrict__ b_rel,
                                  const float* __restrict__ W_root,
                                  const float* __restrict__ W_dec,
                                  const float* __restrict__ b_dec,
                                  float* __restrict__ W_mid,
                                  float* __restrict__ b_mid)
{
    const float w = expf(-1.0f / 9.0f);
    const int idx = blockIdx.x * blockDim.x + threadIdx.x;
    const int nthr = gridDim.x * blockDim.x;

    for (int e = idx; e < HID * IN_DIM; e += nthr) {
        const int o  = e % IN_DIM;
        const int sf = e / IN_DIM;
        const int s  = sf / N_FEAT;
        const int f  = sf % N_FEAT;
        const int sp = (s + 1) % N_NODE;
        const int sm = (s + N_NODE - 1) % N_NODE;
        float acc = 0.0f;
        #pragma unroll
        for (int g = 0; g < N_FEAT; ++g) {
            acc = fmaf(W_root[f * N_FEAT + g], W_dec[(s  * N_FEAT + g) * IN_DIM + o], acc);
            acc = fmaf(w * W_rel[f * N_FEAT + g],
                       W_dec[(sp * N_FEAT + g) * IN_DIM + o] +
                       W_dec[(sm * N_FEAT + g) * IN_DIM + o], acc);
        }
        W_mid[e] = acc;
    }

    for (int o = idx; o < IN_DIM; o += nthr) {
        float acc = b_dec[o];
        #pragma unroll
        for (int t = 0; t < N_NODE; ++t)
            #pragma unroll
            for (int g = 0; g < N_FEAT; ++g)
                acc = fmaf(b_rel[g], W_dec[(t * N_FEAT + g) * IN_DIM + o], acc);
        b_mid[o] = acc;
    }
}

// ---------------------------------------------------------------------------
// Fused bf16-MFMA 2-layer MLP. One 16-row tile per wave per iteration.
// k-mapping f(q,e)=32s+8q+e used consistently for A and B fragments -> result
// is correct for ANY hardware k-permutation (only C/D layout is load-bearing:
// col=lane&15, row=4*(lane>>4)+reg  [HW-verified]).
// Layer1 -> layer2 transpose through a per-wave-PRIVATE LDS strip (no
// __syncthreads needed); stride 84 words keeps LDS conflicts <=2-way (free).
// ---------------------------------------------------------------------------
__global__ __launch_bounds__(256) void fused_mfma_kernel(
    const float* __restrict__ x,
    const float* __restrict__ W_enc,   // [IN_DIM][HID]
    const float* __restrict__ b_enc,   // [HID]
    const float* __restrict__ W_mid,   // [HID][IN_DIM]
    const float* __restrict__ b_mid,   // [IN_DIM]
    float* __restrict__ out,
    int B, int ntiles)
{
    __shared__ float y_lds_all[4][16 * 84];
    const int tid  = threadIdx.x;
    const int wave = tid >> 6;
    const int lane = tid & 63;
    const int m = lane & 15;        // row (A) / col (B,D) index within tile
    const int q = lane >> 4;        // k-group
    float* __restrict__ y_lds = y_lds_all[wave];

    // ---- per-wave weight fragments (gathered once; weights are tiny, L2-hot) ----
    bf16x8 B1[5][2];                // layer-1 B operand: W_enc[k][n], n-tile t, k-step s
    #pragma unroll
    for (int t = 0; t < 5; ++t) {
        #pragma unroll
        for (int s = 0; s < 2; ++s) {
            float tmp[8];
            #pragma unroll
            for (int e = 0; e < 8; ++e) {
                const int k = 32 * s + 8 * q + e;
                tmp[e] = (k < IN_DIM) ? W_enc[k * HID + 16 * t + m] : 0.0f;
            }
            #pragma unroll
            for (int e = 0; e < 8; ++e) B1[t][s][e] = (short)f2bf(tmp[e]);
        }
    }
    bf16x8 B2[3][3];                // layer-2 B operand: W_mid[n][o], o-tile t, k-step s
    #pragma unroll
    for (int t = 0; t < 3; ++t) {
        const int o = 16 * t + m;
        #pragma unroll
        for (int s = 0; s < 3; ++s) {
            float tmp[8];
            #pragma unroll
            for (int e = 0; e < 8; ++e) {
                const int n = 32 * s + 8 * q + e;
                tmp[e] = (n < HID && o < IN_DIM) ? W_mid[n * IN_DIM + o] : 0.0f;
            }
            #pragma unroll
            for (int e = 0; e < 8; ++e) B2[t][s][e] = (short)f2bf(tmp[e]);
        }
    }
    float bias1[5];
    #pragma unroll
    for (int t = 0; t < 5; ++t) bias1[t] = b_enc[16 * t + m];
    float bias2[3];
    #pragma unroll
    for (int t = 0; t < 3; ++t) bias2[t] = (16 * t + m < IN_DIM) ? b_mid[16 * t + m] : 0.0f;

    const int wstride = gridDim.x * 4;
    for (int it = blockIdx.x * 4 + wave; it < ntiles; it += wstride) {
        const float* xt = x + (size_t)it * 16 * IN_DIM;
        const bool okA = ((size_t)(it * 16 + m) < (size_t)B);

        // ---- A fragments from x (coalesced float4 pairs, fp32 -> bf16 RNE) ----
        bf16x8 A0, A1;
        {
            float va[8];
            if (okA) {
                const float4 u0 = *(const float4*)(xt + m * IN_DIM + 8 * q);
                const float4 u1 = *(const float4*)(xt + m * IN_DIM + 8 * q + 4);
                va[0] = u0.x; va[1] = u0.y; va[2] = u0.z; va[3] = u0.w;
                va[4] = u1.x; va[5] = u1.y; va[6] = u1.z; va[7] = u1.w;
            } else {
                #pragma unroll
                for (int e = 0; e < 8; ++e) va[e] = 0.0f;
            }
            #pragma unroll
            for (int e = 0; e < 8; ++e) A0[e] = (short)f2bf(va[e]);
        }
        {
            float va[8];
            if (okA && q == 0) {            // k = 32..39 live only in q==0 slots
                const float4 u0 = *(const float4*)(xt + m * IN_DIM + 32);
                const float4 u1 = *(const float4*)(xt + m * IN_DIM + 36);
                va[0] = u0.x; va[1] = u0.y; va[2] = u0.z; va[3] = u0.w;
                va[4] = u1.x; va[5] = u1.y; va[6] = u1.z; va[7] = u1.w;
            } else {
                #pragma unroll
                for (int e = 0; e < 8; ++e) va[e] = 0.0f;
            }
            #pragma unroll
            for (int e = 0; e < 8; ++e) A1[e] = (short)f2bf(va[e]);
        }

        // ---- layer 1: 5 n-tiles x 2 k-steps ----
        f32x4 acc1[5];
        #pragma unroll
        for (int t = 0; t < 5; ++t) {
            acc1[t][0] = bias1[t]; acc1[t][1] = bias1[t];
            acc1[t][2] = bias1[t]; acc1[t][3] = bias1[t];
        }
        #pragma unroll
        for (int t = 0; t < 5; ++t) {
            acc1[t] = __builtin_amdgcn_mfma_f32_16x16x32_bf16(A0, B1[t][0], acc1[t], 0, 0, 0);
            acc1[t] = __builtin_amdgcn_mfma_f32_16x16x32_bf16(A1, B1[t][1], acc1[t], 0, 0, 0);
        }

        // ---- relu -> wave-private LDS strip (row = 4q+r, col = 16t+m) ----
        #pragma unroll
        for (int t = 0; t < 5; ++t)
            #pragma unroll
            for (int r = 0; r < 4; ++r)
                y_lds[(4 * q + r) * 84 + 16 * t + m] = fmaxf(acc1[t][r], 0.0f);

        asm volatile("s_waitcnt lgkmcnt(0)" ::: "memory");

        // ---- layer-2 A fragments: row m of y, k = 32s+8q+e ----
        bf16x8 A2[3];
        #pragma unroll
        for (int s = 0; s < 3; ++s) {
            float va[8];
            if (s < 2 || q < 2) {           // s==2 valid only for n=64..79 (q<2)
                const float* yp = y_lds + m * 84 + 32 * s + 8 * q;
                const float4 u0 = *(const float4*)(yp);
                const float4 u1 = *(const float4*)(yp + 4);
                va[0] = u0.x; va[1] = u0.y; va[2] = u0.z; va[3] = u0.w;
                va[4] = u1.x; va[5] = u1.y; va[6] = u1.z; va[7] = u1.w;
            } else {
                #pragma unroll
                for (int e = 0; e < 8; ++e) va[e] = 0.0f;
            }
            #pragma unroll
            for (int e = 0; e < 8; ++e) A2[s][e] = (short)f2bf(va[e]);
        }

        // ---- layer 2: 3 o-tiles x 3 k-steps ----
        f32x4 acc2[3];
        #pragma unroll
        for (int t = 0; t < 3; ++t) {
            acc2[t][0] = bias2[t]; acc2[t][1] = bias2[t];
            acc2[t][2] = bias2[t]; acc2[t][3] = bias2[t];
        }
        #pragma unroll
        for (int t = 0; t < 3; ++t)
            #pragma unroll
            for (int s = 0; s < 3; ++s)
                acc2[t] = __builtin_amdgcn_mfma_f32_16x16x32_bf16(A2[s], B2[t][s], acc2[t], 0, 0, 0);

        // ---- relu + store (quarter-wave writes 16 consecutive floats -> coalesced) ----
        #pragma unroll
        for (int t = 0; t < 3; ++t) {
            const int o = 16 * t + m;
            if (o < IN_DIM) {
                #pragma unroll
                for (int r = 0; r < 4; ++r) {
                    const size_t row = (size_t)it * 16 + 4 * q + r;
                    if (row < (size_t)B)
                        out[row * IN_DIM + o] = fmaxf(acc2[t][r], 0.0f);
                }
            }
        }
    }
}

extern "C" void kernel_launch(void* const* d_in, const int* in_sizes, int n_in,
                              void* d_out, int out_size, void* d_ws, size_t ws_size,
                              hipStream_t stream)
{
    const float* x      = (const float*)d_in[0];
    const float* W_enc  = (const float*)d_in[1];
    const float* b_enc  = (const float*)d_in[2];
    const float* W_rel  = (const float*)d_in[3];
    const float* b_rel  = (const float*)d_in[4];
    const float* W_root = (const float*)d_in[5];
    const float* W_dec  = (const float*)d_in[6];
    const float* b_dec  = (const float*)d_in[7];
    float* out = (float*)d_out;

    const int B = in_sizes[0] / IN_DIM;
    const int ntiles = (B + 15) / 16;

    float* W_mid = (float*)d_ws;                 // HID*IN_DIM floats (proven ws fit)
    float* b_mid = W_mid + HID * IN_DIM;         // IN_DIM floats

    precompute_kernel<<<13, 256, 0, stream>>>(W_rel, b_rel, W_root, W_dec, b_dec,
                                              W_mid, b_mid);

    const int grid = 2048;                       // 8192 waves, grid-stride over tiles
    fused_mfma_kernel<<<grid, 256, 0, stream>>>(x, W_enc, b_enc, W_mid, b_mid,
                                                out, B, ntiles);
}